// Round 1
// 1775.638 us; speedup vs baseline: 1.1433x; 1.1433x over previous
//
#include <hip/hip_runtime.h>
#include <hip/hip_bf16.h>
#include <math.h>

#define Bdim 32
#define Ndim 512
#define Hdim 768
#define Rdim 5
#define Ldim 2
#define FFdim 1536
#define LN_EPS 1e-5f

typedef __attribute__((ext_vector_type(8))) __bf16 bf16x8;
typedef __attribute__((ext_vector_type(8))) unsigned short ushort8;
typedef __attribute__((ext_vector_type(4))) float f32x4;

__device__ __forceinline__ unsigned short f2bf(float f) {
  union { float f; unsigned int u; } x;
  x.f = f;
  unsigned int u = x.u;
  return (unsigned short)((u + 0x7FFFu + ((u >> 16) & 1u)) >> 16);  // RTNE
}

__device__ __forceinline__ void gload_lds16(const unsigned short* g, unsigned short* l) {
  __builtin_amdgcn_global_load_lds(
      (const __attribute__((address_space(1))) void*)g,
      (__attribute__((address_space(3))) void*)l, 16, 0, 0);
}

// ---------------------------------------------------------------------------
// MFMA bf16 GEMM: C[M,N] = A[M,K] @ B[K,N]; A bf16 row-major, B TRANSPOSED
// bf16 (Bt[n][k], k-contiguous). 128x128 tile, BK=32, 4 waves.
// All staging via global_load_lds width=16 into linear (unpadded) LDS.
// EPI 0: C = A@B                          (agg, adj pre-normalized) -> bf16
// EPI 1: C (+)= wv * relu(A@B + bias)     (msg + gate merge) -> f32 RMW;
//        OUT_BF16 variant: v += Cf, write bf16 to C2 (final relation)
// EPI 2: C = A@B + bias                   (out proj / ffn2)  -> fp32
// EPI 3: C = relu(A@B + bias)             (ffn1)             -> bf16
// ---------------------------------------------------------------------------
template <int EPI, bool OUT_BF16>
__global__ __launch_bounds__(256) void mfma_gemm(
    const unsigned short* __restrict__ A, long sA, int lda,
    const unsigned short* __restrict__ Bt, long sB, int ldb,
    void* __restrict__ Cp, long sC, int ldc,
    int K,
    const float* __restrict__ bias,
    const float* __restrict__ wv,
    int accumulate,
    unsigned short* __restrict__ C2) {
  __shared__ __align__(16) unsigned short As[128 * 32];
  __shared__ __align__(16) unsigned short Bs[128 * 32];

  const int zb = blockIdx.z;
  const int row0 = blockIdx.y * 128;
  const int col0 = blockIdx.x * 128;
  const int tid = threadIdx.x;
  const int wid = tid >> 6;
  const int lane = tid & 63;
  const int mq = (wid & 1) * 64;   // wave's row quadrant
  const int nq = (wid >> 1) * 64;  // wave's col quadrant
  const int lr = lane & 15;
  const int lk = (lane >> 4) * 8;

  // global_load_lds staging: call c (0..7) covers LDS bytes [c*1024,c*1024+1024)
  // lane l in call c: row = c*16 + (l>>2), elem = (l&3)*8
  // (lds byte c*1024 + l*16 == row*64 + (l&3)*16 for linear [128][32] ushort)
  const int c0 = wid * 2;
  const int srow0 = c0 * 16 + (lane >> 2);
  const int srow1 = srow0 + 16;
  const int se = (lane & 3) * 8;

  const unsigned short* Ab = A + zb * sA;
  const unsigned short* Bb = Bt + zb * sB;
  const unsigned short* Ag0 = Ab + (long)(row0 + srow0) * lda + se;
  const unsigned short* Ag1 = Ab + (long)(row0 + srow1) * lda + se;
  const unsigned short* Bg0 = Bb + (long)(col0 + srow0) * ldb + se;
  const unsigned short* Bg1 = Bb + (long)(col0 + srow1) * ldb + se;
  unsigned short* Al0 = As + c0 * 512;
  unsigned short* Al1 = As + c0 * 512 + 512;
  unsigned short* Bl0 = Bs + c0 * 512;
  unsigned short* Bl1 = Bs + c0 * 512 + 512;

  f32x4 acc[4][4];
#pragma unroll
  for (int i = 0; i < 4; i++)
#pragma unroll
    for (int j = 0; j < 4; j++) acc[i][j] = (f32x4){0.f, 0.f, 0.f, 0.f};

  for (int k0 = 0; k0 < K; k0 += 32) {
    gload_lds16(Ag0 + k0, Al0);
    gload_lds16(Ag1 + k0, Al1);
    gload_lds16(Bg0 + k0, Bl0);
    gload_lds16(Bg1 + k0, Bl1);
    __syncthreads();

    bf16x8 af[4], bfr[4];
#pragma unroll
    for (int i = 0; i < 4; i++) af[i] = *(const bf16x8*)&As[(mq + i * 16 + lr) * 32 + lk];
#pragma unroll
    for (int j = 0; j < 4; j++) bfr[j] = *(const bf16x8*)&Bs[(nq + j * 16 + lr) * 32 + lk];
#pragma unroll
    for (int i = 0; i < 4; i++)
#pragma unroll
      for (int j = 0; j < 4; j++)
        acc[i][j] = __builtin_amdgcn_mfma_f32_16x16x32_bf16(af[i], bfr[j], acc[i][j], 0, 0, 0);
    __syncthreads();
  }

  // ---- epilogue ----
  float bvals[4];
  if (EPI >= 1) {
#pragma unroll
    for (int j = 0; j < 4; j++) bvals[j] = bias[col0 + nq + j * 16 + lr];
  }
  float wval = 0.f;
  if (EPI == 1) wval = wv[(row0 >> 9) * Rdim];

  float* Cf = (float*)Cp;
  unsigned short* Ch = (unsigned short*)Cp;

#pragma unroll
  for (int i = 0; i < 4; i++) {
#pragma unroll
    for (int r = 0; r < 4; r++) {
      const int grow = row0 + mq + i * 16 + (lane >> 4) * 4 + r;
#pragma unroll
      for (int j = 0; j < 4; j++) {
        const int gcol = col0 + nq + j * 16 + lr;
        const long cidx = zb * sC + (long)grow * ldc + gcol;
        float v = acc[i][j][r];
        if (EPI == 1) {
          v = wval * fmaxf(v + bvals[j], 0.f);
          if (accumulate) v += Cf[cidx];
        }
        if (EPI == 2) v += bvals[j];
        if (EPI == 3) v = fmaxf(v + bvals[j], 0.f);
        if (OUT_BF16) {
          if (EPI == 1) C2[cidx] = f2bf(v);
          else Ch[cidx] = f2bf(v);
        } else {
          Cf[cidx] = v;
        }
      }
    }
  }
}

// ---------------------------------------------------------------------------
// transpose + fp32->bf16 convert: in[z][R_][C_] f32 -> out[z][C_][R_] bf16
// ---------------------------------------------------------------------------
__global__ __launch_bounds__(256) void transpose_cvt(
    const float* __restrict__ in, unsigned short* __restrict__ out, int R_, int C_) {
  __shared__ float t[32][33];
  const int z = blockIdx.z;
  const float* ib = in + (long)z * R_ * C_;
  unsigned short* ob = out + (long)z * R_ * C_;
  const int r0 = blockIdx.y * 32, c0 = blockIdx.x * 32;
  const int tx = threadIdx.x & 31, ty = threadIdx.x >> 5;
#pragma unroll
  for (int i = 0; i < 4; i++)
    t[ty + i * 8][tx] = ib[(long)(r0 + ty + i * 8) * C_ + c0 + tx];
  __syncthreads();
#pragma unroll
  for (int i = 0; i < 4; i++)
    ob[(long)(c0 + ty + i * 8) * R_ + r0 + tx] = f2bf(t[tx][ty + i * 8]);
}

// ---------------------------------------------------------------------------
// adjn[b,r,n,:] = bf16( adj[b,r,n,:] / max(rowsum,1) )  — one wave per row
// ---------------------------------------------------------------------------
__global__ __launch_bounds__(256) void norm_adj_kernel(const float* __restrict__ adj,
                                                       unsigned short* __restrict__ out,
                                                       long total_rows) {
  const long w = ((long)blockIdx.x * 256 + threadIdx.x) >> 6;
  const int lane = threadIdx.x & 63;
  if (w >= total_rows) return;
  const float* row = adj + w * Ndim;
  float4 f0 = *(const float4*)(row + lane * 8);
  float4 f1 = *(const float4*)(row + lane * 8 + 4);
  float s = f0.x + f0.y + f0.z + f0.w + f1.x + f1.y + f1.z + f1.w;
#pragma unroll
  for (int off = 32; off; off >>= 1) s += __shfl_xor(s, off, 64);
  const float inv = 1.0f / fmaxf(s, 1.0f);
  ushort8 o = {f2bf(f0.x * inv), f2bf(f0.y * inv), f2bf(f0.z * inv), f2bf(f0.w * inv),
               f2bf(f1.x * inv), f2bf(f1.y * inv), f2bf(f1.z * inv), f2bf(f1.w * inv)};
  *(ushort8*)&out[w * Ndim + lane * 8] = o;
}

// ---------------------------------------------------------------------------
// gate: pooled = mean_n x[b,n,:]; logits = pooled@gW + gb; w = softmax(logits)
// ---------------------------------------------------------------------------
__global__ void gate_kernel(const float* __restrict__ x,
                            const float* __restrict__ gW,
                            const float* __restrict__ gb,
                            float* __restrict__ w_out) {
  __shared__ float pooled[Hdim];
  __shared__ float logits[Rdim];
  const int b = blockIdx.x;
  const int h = threadIdx.x;
  const float* xb = x + (long)b * Ndim * Hdim + h;
  float s = 0.f;
  for (int n = 0; n < Ndim; n++) s += xb[(long)n * Hdim];
  pooled[h] = s * (1.0f / Ndim);
  __syncthreads();
  if (h < Rdim) {
    float acc = gb[h];
    for (int k = 0; k < Hdim; k++) acc += pooled[k] * gW[k * Rdim + h];
    logits[h] = acc;
  }
  __syncthreads();
  if (h == 0) {
    float mx = -1e30f;
    for (int r = 0; r < Rdim; r++) mx = fmaxf(mx, logits[r]);
    float e[Rdim];
    float se = 0.f;
    for (int r = 0; r < Rdim; r++) { e[r] = expf(logits[r] - mx); se += e[r]; }
    for (int r = 0; r < Rdim; r++) w_out[b * Rdim + r] = e[r] / se;
  }
}

// ---------------------------------------------------------------------------
// out = LayerNorm(a + bsrc) * g + beta   — one block (256 thr) per row of 768
// optional bf16 copy of the output (for downstream GEMM A operand)
// ---------------------------------------------------------------------------
__global__ __launch_bounds__(256) void ln_add_kernel(
    const float* __restrict__ A, const float* __restrict__ Bv,
    const float* __restrict__ g, const float* __restrict__ bb,
    float* __restrict__ out, unsigned short* __restrict__ out_bf) {
  __shared__ float red[8];
  const long base = (long)blockIdx.x * Hdim;
  const int t = threadIdx.x;
  float v0 = A[base + t] + Bv[base + t];
  float v1 = A[base + t + 256] + Bv[base + t + 256];
  float v2 = A[base + t + 512] + Bv[base + t + 512];
  float s = v0 + v1 + v2;
  float ss = v0 * v0 + v1 * v1 + v2 * v2;
#pragma unroll
  for (int off = 32; off > 0; off >>= 1) {
    s += __shfl_down(s, off, 64);
    ss += __shfl_down(ss, off, 64);
  }
  const int wid = t >> 6;
  if ((t & 63) == 0) { red[wid] = s; red[4 + wid] = ss; }
  __syncthreads();
  s = red[0] + red[1] + red[2] + red[3];
  ss = red[4] + red[5] + red[6] + red[7];
  const float mu = s * (1.0f / Hdim);
  const float var = ss * (1.0f / Hdim) - mu * mu;
  const float inv = rsqrtf(var + LN_EPS);
  const float o0 = (v0 - mu) * inv * g[t] + bb[t];
  const float o1 = (v1 - mu) * inv * g[t + 256] + bb[t + 256];
  const float o2 = (v2 - mu) * inv * g[t + 512] + bb[t + 512];
  out[base + t] = o0;
  out[base + t + 256] = o1;
  out[base + t + 512] = o2;
  if (out_bf) {
    out_bf[base + t] = f2bf(o0);
    out_bf[base + t + 256] = f2bf(o1);
    out_bf[base + t + 512] = f2bf(o2);
  }
}

// ---------------------------------------------------------------------------
__global__ void stat_kernel(const float* __restrict__ w_buf, float* __restrict__ out) {
  const int r = threadIdx.x;
  if (r < Rdim) {
    float s = 0.f;
    for (int l = 0; l < Ldim; l++)
      for (int b = 0; b < Bdim; b++) s += w_buf[l * Bdim * Rdim + b * Rdim + r];
    out[r] = s * (1.0f / (Ldim * Bdim));
  }
}

extern "C" void kernel_launch(void* const* d_in, const int* in_sizes, int n_in,
                              void* d_out, int out_size, void* d_ws, size_t ws_size,
                              hipStream_t stream) {
  const float* node = (const float*)d_in[0];   // [B,N,H]
  const float* adj  = (const float*)d_in[1];   // [B,R,N,N]
  const float* relW = (const float*)d_in[2];   // [L,R,H,H]
  const float* relb = (const float*)d_in[3];   // [L,R,H]
  const float* gateW = (const float*)d_in[4];  // [L,H,R]
  const float* gateb = (const float*)d_in[5];  // [L,R]
  const float* outW = (const float*)d_in[6];   // [L,H,H]
  const float* outb = (const float*)d_in[7];   // [L,H]
  const float* ln1g = (const float*)d_in[8];
  const float* ln1b = (const float*)d_in[9];
  const float* fW1 = (const float*)d_in[10];   // [L,H,FF]
  const float* fb1 = (const float*)d_in[11];   // [L,FF]
  const float* fW2 = (const float*)d_in[12];   // [L,FF,H]
  const float* fb2 = (const float*)d_in[13];   // [L,H]
  const float* ln2g = (const float*)d_in[14];
  const float* ln2b = (const float*)d_in[15];

  const long BNH = (long)Bdim * Ndim * Hdim;                 // 12,582,912
  const long BRNN = (long)Bdim * Rdim * Ndim * Ndim;         // 41,943,040
  float* xout = (float*)d_out;
  float* stat = xout + BNH;

  // ws layout:
  //   f32: merged | hidden | tmp               (3 x BNH f32)
  //   bf16: agg_bf | xT_bf (alias hidden_bf) | merged_bf | adjn_bf | weightsT
  float* ws = (float*)d_ws;
  float* merged = ws;                          // [B*N,H] f32 accum; later tmp2
  float* hidden = ws + BNH;                    // [B*N,H] f32
  float* tmp    = ws + 2 * BNH;                // [B*N,H] f32; aliased by ffh_bf
  unsigned short* us = (unsigned short*)(ws + 3 * BNH);
  unsigned short* agg_bf = us;                 // [B*N,H] bf16
  unsigned short* xT_bf = us + BNH;            // [B,H,N] bf16 (hidden_bf alias)
  unsigned short* merged_bf = us + 2 * BNH;    // [B*N,H] bf16
  unsigned short* adjn_bf = us + 3 * BNH;      // [B,R,N,N] bf16 (deg-normalized)
  unsigned short* relWT = adjn_bf + BRNN;      // [L*R,H,H] bf16
  unsigned short* outWT = relWT + (long)Ldim * Rdim * Hdim * Hdim;
  unsigned short* W1T = outWT + (long)Ldim * Hdim * Hdim;
  unsigned short* W2T = W1T + (long)Ldim * Hdim * FFdim;
  float* w_buf = (float*)(W2T + (long)Ldim * FFdim * Hdim);
  unsigned short* hidden_bf = xT_bf;              // alias (xT dead after agg)
  unsigned short* ffh_bf = (unsigned short*)tmp;  // [B*N,FF] bf16 (aliases tmp)
  float* tmp2 = merged;                           // aliases merged

  // ---- one-time prep ----
  {
    const long rows = (long)Bdim * Rdim * Ndim;  // 81920
    norm_adj_kernel<<<(int)(rows / 4), 256, 0, stream>>>(adj, adjn_bf, rows);
  }
  transpose_cvt<<<dim3(Hdim / 32, Hdim / 32, Ldim * Rdim), 256, 0, stream>>>(relW, relWT, Hdim, Hdim);
  transpose_cvt<<<dim3(Hdim / 32, Hdim / 32, Ldim), 256, 0, stream>>>(outW, outWT, Hdim, Hdim);
  transpose_cvt<<<dim3(FFdim / 32, Hdim / 32, Ldim), 256, 0, stream>>>(fW1, W1T, Hdim, FFdim);
  transpose_cvt<<<dim3(Hdim / 32, FFdim / 32, Ldim), 256, 0, stream>>>(fW2, W2T, FFdim, Hdim);

  for (int l = 0; l < Ldim; l++) {
    const float* xin = (l == 0) ? node : xout;

    gate_kernel<<<Bdim, Hdim, 0, stream>>>(
        xin, gateW + (long)l * Hdim * Rdim, gateb + (long)l * Rdim,
        w_buf + (long)l * Bdim * Rdim);

    // xT_bf[b][h][n] = x[b][n][h]
    transpose_cvt<<<dim3(Hdim / 32, Ndim / 32, Bdim), 256, 0, stream>>>(xin, xT_bf, Ndim, Hdim);

    for (int r = 0; r < Rdim; r++) {
      // agg_bf[b,n,:] = adjn[b,r] @ x[b]      (deg norm folded into adjn)
      mfma_gemm<0, true><<<dim3(Hdim / 128, Ndim / 128, Bdim), 256, 0, stream>>>(
          adjn_bf + (long)r * Ndim * Ndim, (long)Rdim * Ndim * Ndim, Ndim,
          xT_bf, (long)Hdim * Ndim, Ndim,
          agg_bf, (long)Ndim * Hdim, Hdim,
          Ndim, nullptr, nullptr, 0, nullptr);

      // merged (+)= w[b,r] * relu(agg @ rel_W[l,r] + rel_b[l,r])
      // final relation also emits merged_bf for the out-proj GEMM
      if (r < Rdim - 1) {
        mfma_gemm<1, false><<<dim3(Hdim / 128, (Bdim * Ndim) / 128, 1), 256, 0, stream>>>(
            agg_bf, 0, Hdim,
            relWT + ((long)l * Rdim + r) * Hdim * Hdim, 0, Hdim,
            merged, 0, Hdim,
            Hdim,
            relb + ((long)l * Rdim + r) * Hdim,
            w_buf + (long)l * Bdim * Rdim + r, (r > 0) ? 1 : 0, nullptr);
      } else {
        mfma_gemm<1, true><<<dim3(Hdim / 128, (Bdim * Ndim) / 128, 1), 256, 0, stream>>>(
            agg_bf, 0, Hdim,
            relWT + ((long)l * Rdim + r) * Hdim * Hdim, 0, Hdim,
            merged, 0, Hdim,
            Hdim,
            relb + ((long)l * Rdim + r) * Hdim,
            w_buf + (long)l * Bdim * Rdim + r, 1, merged_bf);
      }
    }

    // tmp = merged @ out_W + out_b
    mfma_gemm<2, false><<<dim3(Hdim / 128, (Bdim * Ndim) / 128, 1), 256, 0, stream>>>(
        merged_bf, 0, Hdim,
        outWT + (long)l * Hdim * Hdim, 0, Hdim,
        tmp, 0, Hdim,
        Hdim,
        outb + (long)l * Hdim, nullptr, 0, nullptr);

    // hidden = LN(xin + tmp)   (+ bf16 copy for ffn1 A)
    ln_add_kernel<<<Bdim * Ndim, 256, 0, stream>>>(
        xin, tmp, ln1g + (long)l * Hdim, ln1b + (long)l * Hdim, hidden, hidden_bf);

    // ffh = relu(hidden @ W1 + b1)  -> bf16 (aliases tmp, now dead)
    mfma_gemm<3, true><<<dim3(FFdim / 128, (Bdim * Ndim) / 128, 1), 256, 0, stream>>>(
        hidden_bf, 0, Hdim,
        W1T + (long)l * Hdim * FFdim, 0, Hdim,
        ffh_bf, 0, FFdim,
        Hdim,
        fb1 + (long)l * FFdim, nullptr, 0, nullptr);

    // tmp2 = ffh @ W2 + b2   (aliases merged, dead after out-proj)
    mfma_gemm<2, false><<<dim3(Hdim / 128, (Bdim * Ndim) / 128, 1), 256, 0, stream>>>(
        ffh_bf, 0, FFdim,
        W2T + (long)l * FFdim * Hdim, 0, FFdim,
        tmp2, 0, Hdim,
        FFdim,
        fb2 + (long)l * Hdim, nullptr, 0, nullptr);

    // x = LN(hidden + tmp2) -> xout
    ln_add_kernel<<<Bdim * Ndim, 256, 0, stream>>>(
        hidden, tmp2, ln2g + (long)l * Hdim, ln2b + (long)l * Hdim, xout, nullptr);
  }

  stat_kernel<<<1, 64, 0, stream>>>(w_buf, stat);
}

// Round 2
// 1688.482 us; speedup vs baseline: 1.2023x; 1.0516x over previous
//
#include <hip/hip_runtime.h>
#include <hip/hip_bf16.h>
#include <math.h>

#define Bdim 32
#define Ndim 512
#define Hdim 768
#define Rdim 5
#define Ldim 2
#define FFdim 1536
#define LN_EPS 1e-5f

typedef __attribute__((ext_vector_type(8))) __bf16 bf16x8;
typedef __attribute__((ext_vector_type(8))) unsigned short ushort8;
typedef __attribute__((ext_vector_type(4))) float f32x4;

__device__ __forceinline__ unsigned short f2bf(float f) {
  union { float f; unsigned int u; } x;
  x.f = f;
  unsigned int u = x.u;
  return (unsigned short)((u + 0x7FFFu + ((u >> 16) & 1u)) >> 16);  // RTNE
}

__device__ __forceinline__ void gload_lds16(const unsigned short* g, unsigned short* l) {
  __builtin_amdgcn_global_load_lds(
      (const __attribute__((address_space(1))) void*)g,
      (__attribute__((address_space(3))) void*)l, 16, 0, 0);
}

// ---------------------------------------------------------------------------
// MFMA bf16 GEMM: C[M,N] = A[M,K] @ B[K,N]; A bf16 row-major, B TRANSPOSED
// bf16 (Bt[n][k], k-contiguous). 128x128 tile, BK=32, 4 waves.
// All staging via global_load_lds width=16 into linear (unpadded) LDS.
// NSEG K-segments of segK each (NSEG=1 for plain GEMM).
// EPI 0: C = A@B                           (agg; z = r*32+b decomposition) -> bf16
// EPI 1: C = sum_seg wv[b,seg]*relu(A_seg@B_seg + bias_seg)  (fused msg)  -> bf16
// EPI 2: C = A@B + bias + resid            (out proj / ffn2)              -> f32
// EPI 3: C = relu(A@B + bias)              (ffn1)                         -> bf16
// ---------------------------------------------------------------------------
template <int EPI, bool OUT_BF16, int NSEG>
__global__ __launch_bounds__(256) void mfma_gemm(
    const unsigned short* __restrict__ A, long sA, long sA2, int lda,
    const unsigned short* __restrict__ Bt, long sB, int ldb,
    void* __restrict__ Cp, long sC, int ldc,
    int segK, long segA, long segB,
    const float* __restrict__ bias,
    const float* __restrict__ resid,
    const float* __restrict__ wv) {
  __shared__ __align__(16) unsigned short As[128 * 32];
  __shared__ __align__(16) unsigned short Bs[128 * 32];

  const int zb = blockIdx.z;
  const int zlo = zb & 31;   // b
  const int zhi = zb >> 5;   // r (agg batching); 0 elsewhere
  const int row0 = blockIdx.y * 128;
  const int col0 = blockIdx.x * 128;
  const int tid = threadIdx.x;
  const int wid = tid >> 6;
  const int lane = tid & 63;
  const int mq = (wid & 1) * 64;   // wave's row quadrant
  const int nq = (wid >> 1) * 64;  // wave's col quadrant
  const int lr = lane & 15;
  const int lk = (lane >> 4) * 8;

  // global_load_lds staging: call c (0..7) covers LDS bytes [c*1024,c*1024+1024)
  // lane l in call c: row = c*16 + (l>>2), elem = (l&3)*8
  const int c0 = wid * 2;
  const int srow0 = c0 * 16 + (lane >> 2);
  const int se = (lane & 3) * 8;

  const unsigned short* Abase = A + (long)zlo * sA + (long)zhi * sA2;
  const unsigned short* Bbase = Bt + (long)zlo * sB;
  unsigned short* Al0 = As + c0 * 512;
  unsigned short* Al1 = As + c0 * 512 + 512;
  unsigned short* Bl0 = Bs + c0 * 512;
  unsigned short* Bl1 = Bs + c0 * 512 + 512;

  f32x4 acc[4][4];
  f32x4 acc2[4][4];
#pragma unroll
  for (int i = 0; i < 4; i++)
#pragma unroll
    for (int j = 0; j < 4; j++) {
      acc[i][j] = (f32x4){0.f, 0.f, 0.f, 0.f};
      if (EPI == 1) acc2[i][j] = (f32x4){0.f, 0.f, 0.f, 0.f};
    }

  for (int seg = 0; seg < NSEG; seg++) {
    const unsigned short* Ag0 = Abase + (long)seg * segA + (long)(row0 + srow0) * lda + se;
    const unsigned short* Ag1 = Ag0 + (long)16 * lda;
    const unsigned short* Bg0 = Bbase + (long)seg * segB + (long)(col0 + srow0) * ldb + se;
    const unsigned short* Bg1 = Bg0 + (long)16 * ldb;

    for (int k0 = 0; k0 < segK; k0 += 32) {
      gload_lds16(Ag0 + k0, Al0);
      gload_lds16(Ag1 + k0, Al1);
      gload_lds16(Bg0 + k0, Bl0);
      gload_lds16(Bg1 + k0, Bl1);
      __syncthreads();

      bf16x8 af[4], bfr[4];
#pragma unroll
      for (int i = 0; i < 4; i++) af[i] = *(const bf16x8*)&As[(mq + i * 16 + lr) * 32 + lk];
#pragma unroll
      for (int j = 0; j < 4; j++) bfr[j] = *(const bf16x8*)&Bs[(nq + j * 16 + lr) * 32 + lk];
#pragma unroll
      for (int i = 0; i < 4; i++)
#pragma unroll
        for (int j = 0; j < 4; j++)
          acc[i][j] = __builtin_amdgcn_mfma_f32_16x16x32_bf16(af[i], bfr[j], acc[i][j], 0, 0, 0);
      __syncthreads();
    }

    if (EPI == 1) {
      // fold this relation's message into acc2, reset acc
      const float wval = wv[(row0 >> 9) * Rdim + seg];
#pragma unroll
      for (int j = 0; j < 4; j++) {
        const float bj = bias[seg * Hdim + col0 + nq + j * 16 + lr];
#pragma unroll
        for (int i = 0; i < 4; i++)
#pragma unroll
          for (int rr = 0; rr < 4; rr++) {
            acc2[i][j][rr] += wval * fmaxf(acc[i][j][rr] + bj, 0.f);
            acc[i][j][rr] = 0.f;
          }
      }
    }
  }

  // ---- epilogue ----
  float bvals[4];
  if (EPI == 2 || EPI == 3) {
#pragma unroll
    for (int j = 0; j < 4; j++) bvals[j] = bias[col0 + nq + j * 16 + lr];
  }

  float* Cf = (float*)Cp;
  unsigned short* Ch = (unsigned short*)Cp;
  const long Coff = (long)zb * sC;

#pragma unroll
  for (int i = 0; i < 4; i++) {
#pragma unroll
    for (int r = 0; r < 4; r++) {
      const int grow = row0 + mq + i * 16 + (lane >> 4) * 4 + r;
#pragma unroll
      for (int j = 0; j < 4; j++) {
        const int gcol = col0 + nq + j * 16 + lr;
        const long cidx = Coff + (long)grow * ldc + gcol;
        float v;
        if (EPI == 1) v = acc2[i][j][r];
        else v = acc[i][j][r];
        if (EPI == 2) v += bvals[j] + resid[cidx];
        if (EPI == 3) v = fmaxf(v + bvals[j], 0.f);
        if (OUT_BF16) Ch[cidx] = f2bf(v);
        else Cf[cidx] = v;
      }
    }
  }
}

// ---------------------------------------------------------------------------
// transpose + fp32->bf16 convert: in[z][R_][C_] f32 -> out[z][C_][R_] bf16
// ---------------------------------------------------------------------------
__global__ __launch_bounds__(256) void transpose_cvt(
    const float* __restrict__ in, unsigned short* __restrict__ out, int R_, int C_) {
  __shared__ float t[32][33];
  const int z = blockIdx.z;
  const float* ib = in + (long)z * R_ * C_;
  unsigned short* ob = out + (long)z * R_ * C_;
  const int r0 = blockIdx.y * 32, c0 = blockIdx.x * 32;
  const int tx = threadIdx.x & 31, ty = threadIdx.x >> 5;
#pragma unroll
  for (int i = 0; i < 4; i++)
    t[ty + i * 8][tx] = ib[(long)(r0 + ty + i * 8) * C_ + c0 + tx];
  __syncthreads();
#pragma unroll
  for (int i = 0; i < 4; i++)
    ob[(long)(c0 + ty + i * 8) * R_ + r0 + tx] = f2bf(t[tx][ty + i * 8]);
}

// ---------------------------------------------------------------------------
// adjn[b,r,n,:] = bf16( adj[b,r,n,:] / max(rowsum,1) )  — one wave per row
// ---------------------------------------------------------------------------
__global__ __launch_bounds__(256) void norm_adj_kernel(const float* __restrict__ adj,
                                                       unsigned short* __restrict__ out,
                                                       long total_rows) {
  const long w = ((long)blockIdx.x * 256 + threadIdx.x) >> 6;
  const int lane = threadIdx.x & 63;
  if (w >= total_rows) return;
  const float* row = adj + w * Ndim;
  float4 f0 = *(const float4*)(row + lane * 8);
  float4 f1 = *(const float4*)(row + lane * 8 + 4);
  float s = f0.x + f0.y + f0.z + f0.w + f1.x + f1.y + f1.z + f1.w;
#pragma unroll
  for (int off = 32; off; off >>= 1) s += __shfl_xor(s, off, 64);
  const float inv = 1.0f / fmaxf(s, 1.0f);
  ushort8 o = {f2bf(f0.x * inv), f2bf(f0.y * inv), f2bf(f0.z * inv), f2bf(f0.w * inv),
               f2bf(f1.x * inv), f2bf(f1.y * inv), f2bf(f1.z * inv), f2bf(f1.w * inv)};
  *(ushort8*)&out[w * Ndim + lane * 8] = o;
}

// ---------------------------------------------------------------------------
// pool partials: part[b][ch][h] = sum_{n in ch*64..+64} x[b,n,h]
// ---------------------------------------------------------------------------
__global__ __launch_bounds__(256) void pool_kernel(const float* __restrict__ x,
                                                   float* __restrict__ part) {
  const int ch = blockIdx.x, b = blockIdx.y, t = threadIdx.x;
  const float* xb = x + ((long)b * Ndim + ch * 64) * Hdim;
  float s0 = 0.f, s1 = 0.f, s2 = 0.f;
  for (int n = 0; n < 64; n++) {
    const float* r = xb + (long)n * Hdim;
    s0 += r[t]; s1 += r[t + 256]; s2 += r[t + 512];
  }
  float* p = part + ((long)b * 8 + ch) * Hdim;
  p[t] = s0; p[t + 256] = s1; p[t + 512] = s2;
}

// ---------------------------------------------------------------------------
// gate: pooled = (sum of partials)/N; logits = pooled@gW + gb; softmax -> w
// ---------------------------------------------------------------------------
__global__ void gate_kernel(const float* __restrict__ part,
                            const float* __restrict__ gW,
                            const float* __restrict__ gb,
                            float* __restrict__ w_out) {
  __shared__ float pooled[Hdim];
  __shared__ float logits[Rdim];
  const int b = blockIdx.x;
  const int h = threadIdx.x;
  float s = 0.f;
#pragma unroll
  for (int c = 0; c < 8; c++) s += part[((long)b * 8 + c) * Hdim + h];
  pooled[h] = s * (1.0f / Ndim);
  __syncthreads();
  if (h < Rdim) {
    float acc = gb[h];
    for (int k = 0; k < Hdim; k++) acc += pooled[k] * gW[k * Rdim + h];
    logits[h] = acc;
  }
  __syncthreads();
  if (h == 0) {
    float mx = -1e30f;
    for (int r = 0; r < Rdim; r++) mx = fmaxf(mx, logits[r]);
    float e[Rdim];
    float se = 0.f;
    for (int r = 0; r < Rdim; r++) { e[r] = expf(logits[r] - mx); se += e[r]; }
    for (int r = 0; r < Rdim; r++) w_out[b * Rdim + r] = e[r] / se;
  }
}

// ---------------------------------------------------------------------------
// out = LayerNorm(X) * g + beta  (single input; residual pre-fused in GEMM)
// ---------------------------------------------------------------------------
__global__ __launch_bounds__(256) void ln_kernel(
    const float* __restrict__ X,
    const float* __restrict__ g, const float* __restrict__ bb,
    float* __restrict__ out, unsigned short* __restrict__ out_bf) {
  __shared__ float red[8];
  const long base = (long)blockIdx.x * Hdim;
  const int t = threadIdx.x;
  float v0 = X[base + t];
  float v1 = X[base + t + 256];
  float v2 = X[base + t + 512];
  float s = v0 + v1 + v2;
  float ss = v0 * v0 + v1 * v1 + v2 * v2;
#pragma unroll
  for (int off = 32; off > 0; off >>= 1) {
    s += __shfl_down(s, off, 64);
    ss += __shfl_down(ss, off, 64);
  }
  const int wid = t >> 6;
  if ((t & 63) == 0) { red[wid] = s; red[4 + wid] = ss; }
  __syncthreads();
  s = red[0] + red[1] + red[2] + red[3];
  ss = red[4] + red[5] + red[6] + red[7];
  const float mu = s * (1.0f / Hdim);
  const float var = ss * (1.0f / Hdim) - mu * mu;
  const float inv = rsqrtf(var + LN_EPS);
  const float o0 = (v0 - mu) * inv * g[t] + bb[t];
  const float o1 = (v1 - mu) * inv * g[t + 256] + bb[t + 256];
  const float o2 = (v2 - mu) * inv * g[t + 512] + bb[t + 512];
  out[base + t] = o0;
  out[base + t + 256] = o1;
  out[base + t + 512] = o2;
  if (out_bf) {
    out_bf[base + t] = f2bf(o0);
    out_bf[base + t + 256] = f2bf(o1);
    out_bf[base + t + 512] = f2bf(o2);
  }
}

// ---------------------------------------------------------------------------
__global__ void stat_kernel(const float* __restrict__ w_buf, float* __restrict__ out) {
  const int r = threadIdx.x;
  if (r < Rdim) {
    float s = 0.f;
    for (int l = 0; l < Ldim; l++)
      for (int b = 0; b < Bdim; b++) s += w_buf[l * Bdim * Rdim + b * Rdim + r];
    out[r] = s * (1.0f / (Ldim * Bdim));
  }
}

extern "C" void kernel_launch(void* const* d_in, const int* in_sizes, int n_in,
                              void* d_out, int out_size, void* d_ws, size_t ws_size,
                              hipStream_t stream) {
  const float* node = (const float*)d_in[0];   // [B,N,H]
  const float* adj  = (const float*)d_in[1];   // [B,R,N,N]
  const float* relW = (const float*)d_in[2];   // [L,R,H,H]
  const float* relb = (const float*)d_in[3];   // [L,R,H]
  const float* gateW = (const float*)d_in[4];  // [L,H,R]
  const float* gateb = (const float*)d_in[5];  // [L,R]
  const float* outW = (const float*)d_in[6];   // [L,H,H]
  const float* outb = (const float*)d_in[7];   // [L,H]
  const float* ln1g = (const float*)d_in[8];
  const float* ln1b = (const float*)d_in[9];
  const float* fW1 = (const float*)d_in[10];   // [L,H,FF]
  const float* fb1 = (const float*)d_in[11];   // [L,FF]
  const float* fW2 = (const float*)d_in[12];   // [L,FF,H]
  const float* fb2 = (const float*)d_in[13];   // [L,H]
  const float* ln2g = (const float*)d_in[14];
  const float* ln2b = (const float*)d_in[15];

  const long BNH = (long)Bdim * Ndim * Hdim;                 // 12,582,912
  const long BRNN = (long)Bdim * Rdim * Ndim * Ndim;         // 41,943,040
  float* xout = (float*)d_out;
  float* stat = xout + BNH;

  // ws layout
  float* ws = (float*)d_ws;
  float* hidden = ws;                          // [B*N,H] f32
  float* tmp    = ws + BNH;                    // [B*N,H] f32; ffh_bf aliases
  unsigned short* agg_all = (unsigned short*)(ws + 2 * BNH);  // [R][B,N,H] bf16
  unsigned short* xT_bf = agg_all + Rdim * BNH;   // [B,H,N] bf16 (hidden_bf alias)
  unsigned short* merged_bf = xT_bf + BNH;        // [B*N,H] bf16
  unsigned short* adjn_bf = merged_bf + BNH;      // [B,R,N,N] bf16
  unsigned short* relWT = adjn_bf + BRNN;         // [L*R,H,H] bf16
  unsigned short* outWT = relWT + (long)Ldim * Rdim * Hdim * Hdim;
  unsigned short* W1T = outWT + (long)Ldim * Hdim * Hdim;
  unsigned short* W2T = W1T + (long)Ldim * Hdim * FFdim;
  float* w_buf = (float*)(W2T + (long)Ldim * FFdim * Hdim);   // [L,B,R]
  float* part = w_buf + Ldim * Bdim * Rdim;                   // [B,8,H]
  unsigned short* hidden_bf = xT_bf;              // alias (xT dead after agg)
  unsigned short* ffh_bf = (unsigned short*)tmp;  // [B*N,FF] bf16 (aliases tmp)
  float* tmp2 = (float*)agg_all;                  // aliases agg_all (dead after msg)

  // ---- one-time prep ----
  {
    const long rows = (long)Bdim * Rdim * Ndim;  // 81920
    norm_adj_kernel<<<(int)(rows / 4), 256, 0, stream>>>(adj, adjn_bf, rows);
  }
  transpose_cvt<<<dim3(Hdim / 32, Hdim / 32, Ldim * Rdim), 256, 0, stream>>>(relW, relWT, Hdim, Hdim);
  transpose_cvt<<<dim3(Hdim / 32, Hdim / 32, Ldim), 256, 0, stream>>>(outW, outWT, Hdim, Hdim);
  transpose_cvt<<<dim3(FFdim / 32, Hdim / 32, Ldim), 256, 0, stream>>>(fW1, W1T, Hdim, FFdim);
  transpose_cvt<<<dim3(Hdim / 32, FFdim / 32, Ldim), 256, 0, stream>>>(fW2, W2T, FFdim, Hdim);

  for (int l = 0; l < Ldim; l++) {
    const float* xin = (l == 0) ? node : xout;

    pool_kernel<<<dim3(8, Bdim), 256, 0, stream>>>(xin, part);
    gate_kernel<<<Bdim, Hdim, 0, stream>>>(
        part, gateW + (long)l * Hdim * Rdim, gateb + (long)l * Rdim,
        w_buf + (long)l * Bdim * Rdim);

    // xT_bf[b][h][n] = x[b][n][h]
    transpose_cvt<<<dim3(Hdim / 32, Ndim / 32, Bdim), 256, 0, stream>>>(xin, xT_bf, Ndim, Hdim);

    // agg_all[r][b] = adjn[b,r] @ x[b]   (all relations, z = r*32+b)
    mfma_gemm<0, true, 1><<<dim3(Hdim / 128, Ndim / 128, Bdim * Rdim), 256, 0, stream>>>(
        adjn_bf, (long)Rdim * Ndim * Ndim, (long)Ndim * Ndim, Ndim,
        xT_bf, (long)Hdim * Ndim, Ndim,
        agg_all, (long)Ndim * Hdim, Hdim,
        Ndim, 0, 0, nullptr, nullptr, nullptr);

    // merged = sum_r w[b,r]*relu(agg_r @ relW[l,r] + relb[l,r])  -> bf16
    mfma_gemm<1, true, Rdim><<<dim3(Hdim / 128, (Bdim * Ndim) / 128, 1), 256, 0, stream>>>(
        agg_all, 0, 0, Hdim,
        relWT + (long)l * Rdim * Hdim * Hdim, 0, Hdim,
        merged_bf, 0, Hdim,
        Hdim, BNH, (long)Hdim * Hdim,
        relb + (long)l * Rdim * Hdim, nullptr,
        w_buf + (long)l * Bdim * Rdim);

    // tmp = merged @ out_W + out_b + xin   (residual fused)
    mfma_gemm<2, false, 1><<<dim3(Hdim / 128, (Bdim * Ndim) / 128, 1), 256, 0, stream>>>(
        merged_bf, 0, 0, Hdim,
        outWT + (long)l * Hdim * Hdim, 0, Hdim,
        tmp, 0, Hdim,
        Hdim, 0, 0,
        outb + (long)l * Hdim, xin, nullptr);

    // hidden = LN(tmp)   (+ bf16 copy for ffn1 A)
    ln_kernel<<<Bdim * Ndim, 256, 0, stream>>>(
        tmp, ln1g + (long)l * Hdim, ln1b + (long)l * Hdim, hidden, hidden_bf);

    // ffh = relu(hidden @ W1 + b1)  -> bf16 (aliases tmp, now dead)
    mfma_gemm<3, true, 1><<<dim3(FFdim / 128, (Bdim * Ndim) / 128, 1), 256, 0, stream>>>(
        hidden_bf, 0, 0, Hdim,
        W1T + (long)l * Hdim * FFdim, 0, Hdim,
        ffh_bf, 0, FFdim,
        Hdim, 0, 0,
        fb1 + (long)l * FFdim, nullptr, nullptr);

    // tmp2 = ffh @ W2 + b2 + hidden  (residual fused; aliases agg_all)
    mfma_gemm<2, false, 1><<<dim3(Hdim / 128, (Bdim * Ndim) / 128, 1), 256, 0, stream>>>(
        ffh_bf, 0, 0, FFdim,
        W2T + (long)l * FFdim * Hdim, 0, FFdim,
        tmp2, 0, Hdim,
        FFdim, 0, 0,
        fb2 + (long)l * Hdim, hidden, nullptr);

    // x = LN(tmp2) -> xout
    ln_kernel<<<Bdim * Ndim, 256, 0, stream>>>(
        tmp2, ln2g + (long)l * Hdim, ln2b + (long)l * Hdim, xout, nullptr);
  }

  stat_kernel<<<1, 64, 0, stream>>>(w_buf, stat);
}

// Round 3
// 1492.841 us; speedup vs baseline: 1.3599x; 1.1311x over previous
//
#include <hip/hip_runtime.h>
#include <hip/hip_bf16.h>
#include <math.h>

#define Bdim 32
#define Ndim 512
#define Hdim 768
#define Rdim 5
#define Ldim 2
#define FFdim 1536
#define LN_EPS 1e-5f

typedef __attribute__((ext_vector_type(8))) __bf16 bf16x8;
typedef __attribute__((ext_vector_type(8))) unsigned short ushort8;
typedef __attribute__((ext_vector_type(4))) float f32x4;

__device__ __forceinline__ unsigned short f2bf(float f) {
  union { float f; unsigned int u; } x;
  x.f = f;
  unsigned int u = x.u;
  return (unsigned short)((u + 0x7FFFu + ((u >> 16) & 1u)) >> 16);  // RTNE
}

__device__ __forceinline__ void gload_lds16(const unsigned short* g, unsigned short* l) {
  __builtin_amdgcn_global_load_lds(
      (const __attribute__((address_space(1))) void*)g,
      (__attribute__((address_space(3))) void*)l, 16, 0, 0);
}

// ---------------------------------------------------------------------------
// MFMA bf16 GEMM: C[M,N] = A[M,K] @ B[K,N]; A bf16 row-major, B TRANSPOSED
// bf16 (Bt[n][k], k-contiguous). 128x128 tile, BK=32, 4 waves.
// Staging via global_load_lds width=16; double-buffered LDS (min 2-phase:
// stage next tile -> other buffer, compute current, single barrier/tile).
// XCD-chunked bijective block remap (T1/m204) for A-panel L2/L3 locality.
// NSEG K-segments of segK each (NSEG=1 for plain GEMM).
// EPI 0: C = A@B                           (agg)              -> bf16
// EPI 1: C = sum_seg wv[b,seg]*relu(A_seg@B_seg + bias_seg)   -> bf16
// EPI 2: C = A@B + bias + resid            (out proj / ffn2)  -> f32
// EPI 3: C = relu(A@B + bias)              (ffn1)             -> bf16
// ---------------------------------------------------------------------------
template <int EPI, bool OUT_BF16, int NSEG>
__global__ __launch_bounds__(256) void mfma_gemm(
    const unsigned short* __restrict__ A, long sA, long sA2, int lda,
    const unsigned short* __restrict__ Bt, long sB, int ldb,
    void* __restrict__ Cp, long sC, int ldc,
    int segK, long segA, long segB,
    const float* __restrict__ bias,
    const float* __restrict__ resid,
    const float* __restrict__ wv) {
  __shared__ __align__(16) unsigned short As0[128 * 32];
  __shared__ __align__(16) unsigned short Bs0[128 * 32];
  __shared__ __align__(16) unsigned short As1[128 * 32];
  __shared__ __align__(16) unsigned short Bs1[128 * 32];

  // ---- XCD-chunked bijective block remap (T1, m204) ----
  const int gx = gridDim.x, gy = gridDim.y;
  int lin = blockIdx.x + gx * (blockIdx.y + gy * blockIdx.z);
  {
    const int total = gx * gy * gridDim.z;
    const int q = total >> 3, r8 = total & 7;
    const int xcd = lin & 7, slot = lin >> 3;
    lin = (xcd < r8) ? (xcd * (q + 1) + slot)
                     : (r8 * (q + 1) + (xcd - r8) * q + slot);
  }
  const int bx = lin % gx;
  const int t2 = lin / gx;
  const int by = t2 % gy;
  const int zb = t2 / gy;

  const int zlo = zb & 31;   // b
  const int zhi = zb >> 5;   // r (agg batching); 0 elsewhere
  const int row0 = by * 128;
  const int col0 = bx * 128;
  const int tid = threadIdx.x;
  const int wid = tid >> 6;
  const int lane = tid & 63;
  const int mq = (wid & 1) * 64;   // wave's row quadrant
  const int nq = (wid >> 1) * 64;  // wave's col quadrant
  const int lr = lane & 15;
  const int lk = (lane >> 4) * 8;

  // global_load_lds staging: wave w covers LDS bytes [w*2048, w*2048+2048)
  // call c (=w*2+i): lane l -> row c*16 + (l>>2), elem (l&3)*8
  const int c0 = wid * 2;
  const int srow0 = c0 * 16 + (lane >> 2);
  const int se = (lane & 3) * 8;

  const unsigned short* Ag0 =
      A + (long)zlo * sA + (long)zhi * sA2 + (long)(row0 + srow0) * lda + se;
  const unsigned short* Ag1 = Ag0 + (long)16 * lda;
  const unsigned short* Bg0 = Bt + (long)zlo * sB + (long)(col0 + srow0) * ldb + se;
  const unsigned short* Bg1 = Bg0 + (long)16 * ldb;

  f32x4 acc[4][4];
  f32x4 acc2[4][4];
#pragma unroll
  for (int i = 0; i < 4; i++)
#pragma unroll
    for (int j = 0; j < 4; j++) {
      acc[i][j] = (f32x4){0.f, 0.f, 0.f, 0.f};
      if (EPI == 1) acc2[i][j] = (f32x4){0.f, 0.f, 0.f, 0.f};
    }

  const int spseg = segK >> 5;
  const int nsteps = NSEG * spseg;
  int sseg = 0, sk = 0;   // staging cursor

  auto stage = [&](unsigned short* Asl, unsigned short* Bsl) {
    const long ao = (long)sseg * segA + sk;
    const long bo = (long)sseg * segB + sk;
    gload_lds16(Ag0 + ao, Asl + c0 * 512);
    gload_lds16(Ag1 + ao, Asl + c0 * 512 + 512);
    gload_lds16(Bg0 + bo, Bsl + c0 * 512);
    gload_lds16(Bg1 + bo, Bsl + c0 * 512 + 512);
    sk += 32;
    if (sk == segK) { sk = 0; sseg++; }
  };

  auto compute = [&](const unsigned short* Asb, const unsigned short* Bsb) {
    bf16x8 af[4], bfr[4];
#pragma unroll
    for (int i = 0; i < 4; i++) af[i] = *(const bf16x8*)&Asb[(mq + i * 16 + lr) * 32 + lk];
#pragma unroll
    for (int j = 0; j < 4; j++) bfr[j] = *(const bf16x8*)&Bsb[(nq + j * 16 + lr) * 32 + lk];
#pragma unroll
    for (int i = 0; i < 4; i++)
#pragma unroll
      for (int j = 0; j < 4; j++)
        acc[i][j] = __builtin_amdgcn_mfma_f32_16x16x32_bf16(af[i], bfr[j], acc[i][j], 0, 0, 0);
  };

  int cnt = 0, cseg = 0;
  auto fold = [&]() {
    // fold this relation's message into acc2, reset acc
    const float wval = wv[(row0 >> 9) * Rdim + cseg];
#pragma unroll
    for (int j = 0; j < 4; j++) {
      const float bj = bias[cseg * Hdim + col0 + nq + j * 16 + lr];
#pragma unroll
      for (int i = 0; i < 4; i++)
#pragma unroll
        for (int rr = 0; rr < 4; rr++) {
          acc2[i][j][rr] += wval * fmaxf(acc[i][j][rr] + bj, 0.f);
          acc[i][j][rr] = 0.f;
        }
    }
    cseg++;
  };

  // prologue: stage step 0 into buffer 0
  stage(As0, Bs0);
  __syncthreads();

  for (int s = 0; s < nsteps; s += 2) {
    if (s + 1 < nsteps) stage(As1, Bs1);   // prefetch next into other buffer
    compute(As0, Bs0);
    if (EPI == 1 && ++cnt == spseg) { fold(); cnt = 0; }
    __syncthreads();
    if (s + 1 < nsteps) {
      if (s + 2 < nsteps) stage(As0, Bs0);
      compute(As1, Bs1);
      if (EPI == 1 && ++cnt == spseg) { fold(); cnt = 0; }
      __syncthreads();
    }
  }

  // ---- epilogue ----
  float bvals[4];
  if (EPI == 2 || EPI == 3) {
#pragma unroll
    for (int j = 0; j < 4; j++) bvals[j] = bias[col0 + nq + j * 16 + lr];
  }

  float* Cf = (float*)Cp;
  unsigned short* Ch = (unsigned short*)Cp;
  const long Coff = (long)zb * sC;

#pragma unroll
  for (int i = 0; i < 4; i++) {
#pragma unroll
    for (int r = 0; r < 4; r++) {
      const int grow = row0 + mq + i * 16 + (lane >> 4) * 4 + r;
#pragma unroll
      for (int j = 0; j < 4; j++) {
        const int gcol = col0 + nq + j * 16 + lr;
        const long cidx = Coff + (long)grow * ldc + gcol;
        float v;
        if (EPI == 1) v = acc2[i][j][r];
        else v = acc[i][j][r];
        if (EPI == 2) v += bvals[j] + resid[cidx];
        if (EPI == 3) v = fmaxf(v + bvals[j], 0.f);
        if (OUT_BF16) Ch[cidx] = f2bf(v);
        else Cf[cidx] = v;
      }
    }
  }
}

// ---------------------------------------------------------------------------
// transpose + fp32->bf16 convert: in[z][R_][C_] f32 -> out[z][C_][R_] bf16
// ---------------------------------------------------------------------------
__global__ __launch_bounds__(256) void transpose_cvt(
    const float* __restrict__ in, unsigned short* __restrict__ out, int R_, int C_) {
  __shared__ float t[32][33];
  const int z = blockIdx.z;
  const float* ib = in + (long)z * R_ * C_;
  unsigned short* ob = out + (long)z * R_ * C_;
  const int r0 = blockIdx.y * 32, c0 = blockIdx.x * 32;
  const int tx = threadIdx.x & 31, ty = threadIdx.x >> 5;
#pragma unroll
  for (int i = 0; i < 4; i++)
    t[ty + i * 8][tx] = ib[(long)(r0 + ty + i * 8) * C_ + c0 + tx];
  __syncthreads();
#pragma unroll
  for (int i = 0; i < 4; i++)
    ob[(long)(c0 + ty + i * 8) * R_ + r0 + tx] = f2bf(t[tx][ty + i * 8]);
}

// ---------------------------------------------------------------------------
// adjn[b,r,n,:] = bf16( adj[b,r,n,:] / max(rowsum,1) )  — one wave per row
// ---------------------------------------------------------------------------
__global__ __launch_bounds__(256) void norm_adj_kernel(const float* __restrict__ adj,
                                                       unsigned short* __restrict__ out,
                                                       long total_rows) {
  const long w = ((long)blockIdx.x * 256 + threadIdx.x) >> 6;
  const int lane = threadIdx.x & 63;
  if (w >= total_rows) return;
  const float* row = adj + w * Ndim;
  float4 f0 = *(const float4*)(row + lane * 8);
  float4 f1 = *(const float4*)(row + lane * 8 + 4);
  float s = f0.x + f0.y + f0.z + f0.w + f1.x + f1.y + f1.z + f1.w;
#pragma unroll
  for (int off = 32; off; off >>= 1) s += __shfl_xor(s, off, 64);
  const float inv = 1.0f / fmaxf(s, 1.0f);
  ushort8 o = {f2bf(f0.x * inv), f2bf(f0.y * inv), f2bf(f0.z * inv), f2bf(f0.w * inv),
               f2bf(f1.x * inv), f2bf(f1.y * inv), f2bf(f1.z * inv), f2bf(f1.w * inv)};
  *(ushort8*)&out[w * Ndim + lane * 8] = o;
}

// ---------------------------------------------------------------------------
// pool partials: part[b][ch][h] = sum_{n in ch*64..+64} x[b,n,h]
// ---------------------------------------------------------------------------
__global__ __launch_bounds__(256) void pool_kernel(const float* __restrict__ x,
                                                   float* __restrict__ part) {
  const int ch = blockIdx.x, b = blockIdx.y, t = threadIdx.x;
  const float* xb = x + ((long)b * Ndim + ch * 64) * Hdim;
  float s0 = 0.f, s1 = 0.f, s2 = 0.f;
  for (int n = 0; n < 64; n++) {
    const float* r = xb + (long)n * Hdim;
    s0 += r[t]; s1 += r[t + 256]; s2 += r[t + 512];
  }
  float* p = part + ((long)b * 8 + ch) * Hdim;
  p[t] = s0; p[t + 256] = s1; p[t + 512] = s2;
}

// ---------------------------------------------------------------------------
// gate: pooled = (sum of partials)/N; logits = pooled@gW + gb; softmax -> w
// ---------------------------------------------------------------------------
__global__ void gate_kernel(const float* __restrict__ part,
                            const float* __restrict__ gW,
                            const float* __restrict__ gb,
                            float* __restrict__ w_out) {
  __shared__ float pooled[Hdim];
  __shared__ float logits[Rdim];
  const int b = blockIdx.x;
  const int h = threadIdx.x;
  float s = 0.f;
#pragma unroll
  for (int c = 0; c < 8; c++) s += part[((long)b * 8 + c) * Hdim + h];
  pooled[h] = s * (1.0f / Ndim);
  __syncthreads();
  if (h < Rdim) {
    float acc = gb[h];
    for (int k = 0; k < Hdim; k++) acc += pooled[k] * gW[k * Rdim + h];
    logits[h] = acc;
  }
  __syncthreads();
  if (h == 0) {
    float mx = -1e30f;
    for (int r = 0; r < Rdim; r++) mx = fmaxf(mx, logits[r]);
    float e[Rdim];
    float se = 0.f;
    for (int r = 0; r < Rdim; r++) { e[r] = expf(logits[r] - mx); se += e[r]; }
    for (int r = 0; r < Rdim; r++) w_out[b * Rdim + r] = e[r] / se;
  }
}

// ---------------------------------------------------------------------------
// out = LayerNorm(X) * g + beta  (single input; residual pre-fused in GEMM)
// ---------------------------------------------------------------------------
__global__ __launch_bounds__(256) void ln_kernel(
    const float* __restrict__ X,
    const float* __restrict__ g, const float* __restrict__ bb,
    float* __restrict__ out, unsigned short* __restrict__ out_bf) {
  __shared__ float red[8];
  const long base = (long)blockIdx.x * Hdim;
  const int t = threadIdx.x;
  float v0 = X[base + t];
  float v1 = X[base + t + 256];
  float v2 = X[base + t + 512];
  float s = v0 + v1 + v2;
  float ss = v0 * v0 + v1 * v1 + v2 * v2;
#pragma unroll
  for (int off = 32; off > 0; off >>= 1) {
    s += __shfl_down(s, off, 64);
    ss += __shfl_down(ss, off, 64);
  }
  const int wid = t >> 6;
  if ((t & 63) == 0) { red[wid] = s; red[4 + wid] = ss; }
  __syncthreads();
  s = red[0] + red[1] + red[2] + red[3];
  ss = red[4] + red[5] + red[6] + red[7];
  const float mu = s * (1.0f / Hdim);
  const float var = ss * (1.0f / Hdim) - mu * mu;
  const float inv = rsqrtf(var + LN_EPS);
  const float o0 = (v0 - mu) * inv * g[t] + bb[t];
  const float o1 = (v1 - mu) * inv * g[t + 256] + bb[t + 256];
  const float o2 = (v2 - mu) * inv * g[t + 512] + bb[t + 512];
  out[base + t] = o0;
  out[base + t + 256] = o1;
  out[base + t + 512] = o2;
  if (out_bf) {
    out_bf[base + t] = f2bf(o0);
    out_bf[base + t + 256] = f2bf(o1);
    out_bf[base + t + 512] = f2bf(o2);
  }
}

// ---------------------------------------------------------------------------
__global__ void stat_kernel(const float* __restrict__ w_buf, float* __restrict__ out) {
  const int r = threadIdx.x;
  if (r < Rdim) {
    float s = 0.f;
    for (int l = 0; l < Ldim; l++)
      for (int b = 0; b < Bdim; b++) s += w_buf[l * Bdim * Rdim + b * Rdim + r];
    out[r] = s * (1.0f / (Ldim * Bdim));
  }
}

extern "C" void kernel_launch(void* const* d_in, const int* in_sizes, int n_in,
                              void* d_out, int out_size, void* d_ws, size_t ws_size,
                              hipStream_t stream) {
  const float* node = (const float*)d_in[0];   // [B,N,H]
  const float* adj  = (const float*)d_in[1];   // [B,R,N,N]
  const float* relW = (const float*)d_in[2];   // [L,R,H,H]
  const float* relb = (const float*)d_in[3];   // [L,R,H]
  const float* gateW = (const float*)d_in[4];  // [L,H,R]
  const float* gateb = (const float*)d_in[5];  // [L,R]
  const float* outW = (const float*)d_in[6];   // [L,H,H]
  const float* outb = (const float*)d_in[7];   // [L,H]
  const float* ln1g = (const float*)d_in[8];
  const float* ln1b = (const float*)d_in[9];
  const float* fW1 = (const float*)d_in[10];   // [L,H,FF]
  const float* fb1 = (const float*)d_in[11];   // [L,FF]
  const float* fW2 = (const float*)d_in[12];   // [L,FF,H]
  const float* fb2 = (const float*)d_in[13];   // [L,H]
  const float* ln2g = (const float*)d_in[14];
  const float* ln2b = (const float*)d_in[15];

  const long BNH = (long)Bdim * Ndim * Hdim;                 // 12,582,912
  const long BRNN = (long)Bdim * Rdim * Ndim * Ndim;         // 41,943,040
  float* xout = (float*)d_out;
  float* stat = xout + BNH;

  // ws layout
  float* ws = (float*)d_ws;
  float* hidden = ws;                          // [B*N,H] f32
  float* tmp    = ws + BNH;                    // [B*N,H] f32; ffh_bf aliases
  unsigned short* agg_all = (unsigned short*)(ws + 2 * BNH);  // [R][B,N,H] bf16
  unsigned short* xT_bf = agg_all + Rdim * BNH;   // [B,H,N] bf16 (hidden_bf alias)
  unsigned short* merged_bf = xT_bf + BNH;        // [B*N,H] bf16
  unsigned short* adjn_bf = merged_bf + BNH;      // [B,R,N,N] bf16
  unsigned short* relWT = adjn_bf + BRNN;         // [L*R,H,H] bf16
  unsigned short* outWT = relWT + (long)Ldim * Rdim * Hdim * Hdim;
  unsigned short* W1T = outWT + (long)Ldim * Hdim * Hdim;
  unsigned short* W2T = W1T + (long)Ldim * Hdim * FFdim;
  float* w_buf = (float*)(W2T + (long)Ldim * FFdim * Hdim);   // [L,B,R]
  float* part = w_buf + Ldim * Bdim * Rdim;                   // [B,8,H]
  unsigned short* hidden_bf = xT_bf;              // alias (xT dead after agg)
  unsigned short* ffh_bf = (unsigned short*)tmp;  // [B*N,FF] bf16 (aliases tmp)
  float* tmp2 = (float*)agg_all;                  // aliases agg_all (dead after msg)

  // ---- one-time prep ----
  {
    const long rows = (long)Bdim * Rdim * Ndim;  // 81920
    norm_adj_kernel<<<(int)(rows / 4), 256, 0, stream>>>(adj, adjn_bf, rows);
  }
  transpose_cvt<<<dim3(Hdim / 32, Hdim / 32, Ldim * Rdim), 256, 0, stream>>>(relW, relWT, Hdim, Hdim);
  transpose_cvt<<<dim3(Hdim / 32, Hdim / 32, Ldim), 256, 0, stream>>>(outW, outWT, Hdim, Hdim);
  transpose_cvt<<<dim3(FFdim / 32, Hdim / 32, Ldim), 256, 0, stream>>>(fW1, W1T, Hdim, FFdim);
  transpose_cvt<<<dim3(Hdim / 32, FFdim / 32, Ldim), 256, 0, stream>>>(fW2, W2T, FFdim, Hdim);

  for (int l = 0; l < Ldim; l++) {
    const float* xin = (l == 0) ? node : xout;

    pool_kernel<<<dim3(8, Bdim), 256, 0, stream>>>(xin, part);
    gate_kernel<<<Bdim, Hdim, 0, stream>>>(
        part, gateW + (long)l * Hdim * Rdim, gateb + (long)l * Rdim,
        w_buf + (long)l * Bdim * Rdim);

    // xT_bf[b][h][n] = x[b][n][h]
    transpose_cvt<<<dim3(Hdim / 32, Ndim / 32, Bdim), 256, 0, stream>>>(xin, xT_bf, Ndim, Hdim);

    // agg_all[r][b] = adjn[b,r] @ x[b]   (all relations, z = r*32+b)
    mfma_gemm<0, true, 1><<<dim3(Hdim / 128, Ndim / 128, Bdim * Rdim), 256, 0, stream>>>(
        adjn_bf, (long)Rdim * Ndim * Ndim, (long)Ndim * Ndim, Ndim,
        xT_bf, (long)Hdim * Ndim, Ndim,
        agg_all, (long)Ndim * Hdim, Hdim,
        Ndim, 0, 0, nullptr, nullptr, nullptr);

    // merged = sum_r w[b,r]*relu(agg_r @ relW[l,r] + relb[l,r])  -> bf16
    mfma_gemm<1, true, Rdim><<<dim3(Hdim / 128, (Bdim * Ndim) / 128, 1), 256, 0, stream>>>(
        agg_all, 0, 0, Hdim,
        relWT + (long)l * Rdim * Hdim * Hdim, 0, Hdim,
        merged_bf, 0, Hdim,
        Hdim, BNH, (long)Hdim * Hdim,
        relb + (long)l * Rdim * Hdim, nullptr,
        w_buf + (long)l * Bdim * Rdim);

    // tmp = merged @ out_W + out_b + xin   (residual fused)
    mfma_gemm<2, false, 1><<<dim3(Hdim / 128, (Bdim * Ndim) / 128, 1), 256, 0, stream>>>(
        merged_bf, 0, 0, Hdim,
        outWT + (long)l * Hdim * Hdim, 0, Hdim,
        tmp, 0, Hdim,
        Hdim, 0, 0,
        outb + (long)l * Hdim, xin, nullptr);

    // hidden = LN(tmp)   (+ bf16 copy for ffn1 A)
    ln_kernel<<<Bdim * Ndim, 256, 0, stream>>>(
        tmp, ln1g + (long)l * Hdim, ln1b + (long)l * Hdim, hidden, hidden_bf);

    // ffh = relu(hidden @ W1 + b1)  -> bf16 (aliases tmp, now dead)
    mfma_gemm<3, true, 1><<<dim3(FFdim / 128, (Bdim * Ndim) / 128, 1), 256, 0, stream>>>(
        hidden_bf, 0, 0, Hdim,
        W1T + (long)l * Hdim * FFdim, 0, Hdim,
        ffh_bf, 0, FFdim,
        Hdim, 0, 0,
        fb1 + (long)l * FFdim, nullptr, nullptr);

    // tmp2 = ffh @ W2 + b2 + hidden  (residual fused; aliases agg_all)
    mfma_gemm<2, false, 1><<<dim3(Hdim / 128, (Bdim * Ndim) / 128, 1), 256, 0, stream>>>(
        ffh_bf, 0, 0, FFdim,
        W2T + (long)l * FFdim * Hdim, 0, FFdim,
        tmp2, 0, Hdim,
        FFdim, 0, 0,
        fb2 + (long)l * Hdim, hidden, nullptr);

    // x = LN(tmp2) -> xout
    ln_kernel<<<Bdim * Ndim, 256, 0, stream>>>(
        tmp2, ln2g + (long)l * Hdim, ln2b + (long)l * Hdim, xout, nullptr);
  }

  stat_kernel<<<1, 64, 0, stream>>>(w_buf, stat);
}

// Round 4
// 1364.887 us; speedup vs baseline: 1.4873x; 1.0937x over previous
//
#include <hip/hip_runtime.h>
#include <hip/hip_bf16.h>
#include <math.h>

#define Bdim 32
#define Ndim 512
#define Hdim 768
#define Rdim 5
#define Ldim 2
#define FFdim 1536
#define LN_EPS 1e-5f

typedef __attribute__((ext_vector_type(8))) __bf16 bf16x8;
typedef __attribute__((ext_vector_type(8))) unsigned short ushort8;
typedef __attribute__((ext_vector_type(4))) float f32x4;

__device__ __forceinline__ unsigned short f2bf(float f) {
  union { float f; unsigned int u; } x;
  x.f = f;
  unsigned int u = x.u;
  return (unsigned short)((u + 0x7FFFu + ((u >> 16) & 1u)) >> 16);  // RTNE
}

__device__ __forceinline__ void gload_lds16(const unsigned short* g, unsigned short* l) {
  __builtin_amdgcn_global_load_lds(
      (const __attribute__((address_space(1))) void*)g,
      (__attribute__((address_space(3))) void*)l, 16, 0, 0);
}

// ---------------------------------------------------------------------------
// MFMA bf16 GEMM: C[M,N] = A[M,K] @ B[K,N]; A bf16 row-major, B TRANSPOSED
// bf16 (Bt[n][k], k-contiguous). 128x128 tile, BK=32, 4 waves.
// 3-deep software pipeline: 3 LDS buffers, counted s_waitcnt vmcnt(8)
// (never 0 in steady state), raw s_barrier pair per step, setprio around
// the MFMA cluster. Staging via global_load_lds width=16, linear LDS.
// XCD-chunked bijective block remap (T1/m204) for A-panel L2/L3 locality.
// NSEG K-segments of segK each (NSEG=1 for plain GEMM).
// EPI 0: C = A@B                           (agg)              -> bf16
// EPI 1: C = sum_seg wv[b,seg]*relu(A_seg@B_seg + bias_seg)   -> bf16
// EPI 2: C = A@B + bias + resid            (out proj / ffn2)  -> f32
// EPI 3: C = relu(A@B + bias)              (ffn1)             -> bf16
// ---------------------------------------------------------------------------
template <int EPI, bool OUT_BF16, int NSEG>
__global__ __launch_bounds__(256, (EPI == 1) ? 2 : 3) void mfma_gemm(
    const unsigned short* __restrict__ A, long sA, long sA2, int lda,
    const unsigned short* __restrict__ Bt, long sB, int ldb,
    void* __restrict__ Cp, long sC, int ldc,
    int segK, long segA, long segB,
    const float* __restrict__ bias,
    const float* __restrict__ resid,
    const float* __restrict__ wv) {
  __shared__ __align__(16) unsigned short As[3 * 128 * 32];
  __shared__ __align__(16) unsigned short Bs[3 * 128 * 32];

  // ---- XCD-chunked bijective block remap (T1, m204) ----
  const int gx = gridDim.x, gy = gridDim.y;
  int lin = blockIdx.x + gx * (blockIdx.y + gy * blockIdx.z);
  {
    const int total = gx * gy * gridDim.z;
    const int q = total >> 3, r8 = total & 7;
    const int xcd = lin & 7, slot = lin >> 3;
    lin = (xcd < r8) ? (xcd * (q + 1) + slot)
                     : (r8 * (q + 1) + (xcd - r8) * q + slot);
  }
  const int bx = lin % gx;
  const int t2 = lin / gx;
  const int by = t2 % gy;
  const int zb = t2 / gy;

  const int zlo = zb & 31;   // b
  const int zhi = zb >> 5;   // r (agg batching); 0 elsewhere
  const int row0 = by * 128;
  const int col0 = bx * 128;
  const int tid = threadIdx.x;
  const int wid = tid >> 6;
  const int lane = tid & 63;
  const int mq = (wid & 1) * 64;   // wave's row quadrant
  const int nq = (wid >> 1) * 64;  // wave's col quadrant
  const int lr = lane & 15;
  const int lk = (lane >> 4) * 8;

  // global_load_lds staging: wave w covers LDS bytes [w*2048, w*2048+2048)
  // call c (=w*2+i): lane l -> row c*16 + (l>>2), elem (l&3)*8
  const int c0 = wid * 2;
  const int srow0 = c0 * 16 + (lane >> 2);
  const int se = (lane & 3) * 8;

  const unsigned short* Ag0 =
      A + (long)zlo * sA + (long)zhi * sA2 + (long)(row0 + srow0) * lda + se;
  const unsigned short* Ag1 = Ag0 + (long)16 * lda;
  const unsigned short* Bg0 = Bt + (long)zlo * sB + (long)(col0 + srow0) * ldb + se;
  const unsigned short* Bg1 = Bg0 + (long)16 * ldb;

  f32x4 acc[4][4];
  f32x4 acc2[4][4];
#pragma unroll
  for (int i = 0; i < 4; i++)
#pragma unroll
    for (int j = 0; j < 4; j++) {
      acc[i][j] = (f32x4){0.f, 0.f, 0.f, 0.f};
      if (EPI == 1) acc2[i][j] = (f32x4){0.f, 0.f, 0.f, 0.f};
    }

  const int spseg = segK >> 5;
  const int nsteps = NSEG * spseg;   // all call sites have nsteps >= 16
  int sseg = 0, sk = 0;              // staging cursor

  auto stage = [&](int buf) {
    unsigned short* Asl = As + buf * 4096 + c0 * 512;
    unsigned short* Bsl = Bs + buf * 4096 + c0 * 512;
    const long ao = (long)sseg * segA + sk;
    const long bo = (long)sseg * segB + sk;
    gload_lds16(Ag0 + ao, Asl);
    gload_lds16(Ag1 + ao, Asl + 512);
    gload_lds16(Bg0 + bo, Bsl);
    gload_lds16(Bg1 + bo, Bsl + 512);
    sk += 32;
    if (sk == segK) { sk = 0; sseg++; }
  };

  int cnt = 0, cseg = 0;
  auto fold = [&]() {
    // fold this relation's message into acc2, reset acc
    const float wval = wv[(row0 >> 9) * Rdim + cseg];
#pragma unroll
    for (int j = 0; j < 4; j++) {
      const float bj = bias[cseg * Hdim + col0 + nq + j * 16 + lr];
#pragma unroll
      for (int i = 0; i < 4; i++)
#pragma unroll
        for (int rr = 0; rr < 4; rr++) {
          acc2[i][j][rr] += wval * fmaxf(acc[i][j][rr] + bj, 0.f);
          acc[i][j][rr] = 0.f;
        }
    }
    cseg++;
  };

  // prologue: 3 K-steps in flight (12 loads outstanding per wave)
  stage(0); stage(1); stage(2);

  int buf = 0;
  for (int s = 0; s < nsteps; ++s) {
    // drain exactly step-s's 4 loads; keep the younger prefetches in flight
    const int rem = nsteps - s;
    if (rem > 2)       asm volatile("s_waitcnt vmcnt(8)" ::: "memory");
    else if (rem == 2) asm volatile("s_waitcnt vmcnt(4)" ::: "memory");
    else               asm volatile("s_waitcnt vmcnt(0)" ::: "memory");
    __builtin_amdgcn_s_barrier();   // all waves' buf-cur writes landed

    const unsigned short* Asb = As + buf * 4096;
    const unsigned short* Bsb = Bs + buf * 4096;
    bf16x8 af[4], bfr[4];
#pragma unroll
    for (int i = 0; i < 4; i++) af[i] = *(const bf16x8*)&Asb[(mq + i * 16 + lr) * 32 + lk];
#pragma unroll
    for (int j = 0; j < 4; j++) bfr[j] = *(const bf16x8*)&Bsb[(nq + j * 16 + lr) * 32 + lk];
    asm volatile("s_waitcnt lgkmcnt(0)" ::: "memory");
    __builtin_amdgcn_sched_barrier(0);
    __builtin_amdgcn_s_barrier();   // all waves done reading buf -> safe to overwrite

    if (s + 3 < nsteps) stage(buf);  // refill oldest buffer (joins vm queue)

    __builtin_amdgcn_s_setprio(1);
#pragma unroll
    for (int i = 0; i < 4; i++)
#pragma unroll
      for (int j = 0; j < 4; j++)
        acc[i][j] = __builtin_amdgcn_mfma_f32_16x16x32_bf16(af[i], bfr[j], acc[i][j], 0, 0, 0);
    __builtin_amdgcn_s_setprio(0);

    if (EPI == 1 && ++cnt == spseg) { fold(); cnt = 0; }
    buf = (buf == 2) ? 0 : buf + 1;
  }

  // ---- epilogue ----
  float bvals[4];
  if (EPI == 2 || EPI == 3) {
#pragma unroll
    for (int j = 0; j < 4; j++) bvals[j] = bias[col0 + nq + j * 16 + lr];
  }

  float* Cf = (float*)Cp;
  unsigned short* Ch = (unsigned short*)Cp;
  const long Coff = (long)zb * sC;

#pragma unroll
  for (int i = 0; i < 4; i++) {
#pragma unroll
    for (int r = 0; r < 4; r++) {
      const int grow = row0 + mq + i * 16 + (lane >> 4) * 4 + r;
#pragma unroll
      for (int j = 0; j < 4; j++) {
        const int gcol = col0 + nq + j * 16 + lr;
        const long cidx = Coff + (long)grow * ldc + gcol;
        float v;
        if (EPI == 1) v = acc2[i][j][r];
        else v = acc[i][j][r];
        if (EPI == 2) v += bvals[j] + resid[cidx];
        if (EPI == 3) v = fmaxf(v + bvals[j], 0.f);
        if (OUT_BF16) Ch[cidx] = f2bf(v);
        else Cf[cidx] = v;
      }
    }
  }
}

// ---------------------------------------------------------------------------
// transpose + fp32->bf16 convert: in[z][R_][C_] f32 -> out[z][C_][R_] bf16
// ---------------------------------------------------------------------------
__global__ __launch_bounds__(256) void transpose_cvt(
    const float* __restrict__ in, unsigned short* __restrict__ out, int R_, int C_) {
  __shared__ float t[32][33];
  const int z = blockIdx.z;
  const float* ib = in + (long)z * R_ * C_;
  unsigned short* ob = out + (long)z * R_ * C_;
  const int r0 = blockIdx.y * 32, c0 = blockIdx.x * 32;
  const int tx = threadIdx.x & 31, ty = threadIdx.x >> 5;
#pragma unroll
  for (int i = 0; i < 4; i++)
    t[ty + i * 8][tx] = ib[(long)(r0 + ty + i * 8) * C_ + c0 + tx];
  __syncthreads();
#pragma unroll
  for (int i = 0; i < 4; i++)
    ob[(long)(c0 + ty + i * 8) * R_ + r0 + tx] = f2bf(t[tx][ty + i * 8]);
}

// ---------------------------------------------------------------------------
// adjn[b,r,n,:] = bf16( adj[b,r,n,:] / max(rowsum,1) )  — one wave per row
// ---------------------------------------------------------------------------
__global__ __launch_bounds__(256) void norm_adj_kernel(const float* __restrict__ adj,
                                                       unsigned short* __restrict__ out,
                                                       long total_rows) {
  const long w = ((long)blockIdx.x * 256 + threadIdx.x) >> 6;
  const int lane = threadIdx.x & 63;
  if (w >= total_rows) return;
  const float* row = adj + w * Ndim;
  float4 f0 = *(const float4*)(row + lane * 8);
  float4 f1 = *(const float4*)(row + lane * 8 + 4);
  float s = f0.x + f0.y + f0.z + f0.w + f1.x + f1.y + f1.z + f1.w;
#pragma unroll
  for (int off = 32; off; off >>= 1) s += __shfl_xor(s, off, 64);
  const float inv = 1.0f / fmaxf(s, 1.0f);
  ushort8 o = {f2bf(f0.x * inv), f2bf(f0.y * inv), f2bf(f0.z * inv), f2bf(f0.w * inv),
               f2bf(f1.x * inv), f2bf(f1.y * inv), f2bf(f1.z * inv), f2bf(f1.w * inv)};
  *(ushort8*)&out[w * Ndim + lane * 8] = o;
}

// ---------------------------------------------------------------------------
// pool partials: part[b][ch][h] = sum_{n in ch*64..+64} x[b,n,h]
// ---------------------------------------------------------------------------
__global__ __launch_bounds__(256) void pool_kernel(const float* __restrict__ x,
                                                   float* __restrict__ part) {
  const int ch = blockIdx.x, b = blockIdx.y, t = threadIdx.x;
  const float* xb = x + ((long)b * Ndim + ch * 64) * Hdim;
  float s0 = 0.f, s1 = 0.f, s2 = 0.f;
  for (int n = 0; n < 64; n++) {
    const float* r = xb + (long)n * Hdim;
    s0 += r[t]; s1 += r[t + 256]; s2 += r[t + 512];
  }
  float* p = part + ((long)b * 8 + ch) * Hdim;
  p[t] = s0; p[t + 256] = s1; p[t + 512] = s2;
}

// ---------------------------------------------------------------------------
// gate: pooled = (sum of partials)/N; logits = pooled@gW + gb; softmax -> w
// ---------------------------------------------------------------------------
__global__ void gate_kernel(const float* __restrict__ part,
                            const float* __restrict__ gW,
                            const float* __restrict__ gb,
                            float* __restrict__ w_out) {
  __shared__ float pooled[Hdim];
  __shared__ float logits[Rdim];
  const int b = blockIdx.x;
  const int h = threadIdx.x;
  float s = 0.f;
#pragma unroll
  for (int c = 0; c < 8; c++) s += part[((long)b * 8 + c) * Hdim + h];
  pooled[h] = s * (1.0f / Ndim);
  __syncthreads();
  if (h < Rdim) {
    float acc = gb[h];
    for (int k = 0; k < Hdim; k++) acc += pooled[k] * gW[k * Rdim + h];
    logits[h] = acc;
  }
  __syncthreads();
  if (h == 0) {
    float mx = -1e30f;
    for (int r = 0; r < Rdim; r++) mx = fmaxf(mx, logits[r]);
    float e[Rdim];
    float se = 0.f;
    for (int r = 0; r < Rdim; r++) { e[r] = expf(logits[r] - mx); se += e[r]; }
    for (int r = 0; r < Rdim; r++) w_out[b * Rdim + r] = e[r] / se;
  }
}

// ---------------------------------------------------------------------------
// out = LayerNorm(X) * g + beta  (single input; residual pre-fused in GEMM)
// ---------------------------------------------------------------------------
__global__ __launch_bounds__(256) void ln_kernel(
    const float* __restrict__ X,
    const float* __restrict__ g, const float* __restrict__ bb,
    float* __restrict__ out, unsigned short* __restrict__ out_bf) {
  __shared__ float red[8];
  const long base = (long)blockIdx.x * Hdim;
  const int t = threadIdx.x;
  float v0 = X[base + t];
  float v1 = X[base + t + 256];
  float v2 = X[base + t + 512];
  float s = v0 + v1 + v2;
  float ss = v0 * v0 + v1 * v1 + v2 * v2;
#pragma unroll
  for (int off = 32; off > 0; off >>= 1) {
    s += __shfl_down(s, off, 64);
    ss += __shfl_down(ss, off, 64);
  }
  const int wid = t >> 6;
  if ((t & 63) == 0) { red[wid] = s; red[4 + wid] = ss; }
  __syncthreads();
  s = red[0] + red[1] + red[2] + red[3];
  ss = red[4] + red[5] + red[6] + red[7];
  const float mu = s * (1.0f / Hdim);
  const float var = ss * (1.0f / Hdim) - mu * mu;
  const float inv = rsqrtf(var + LN_EPS);
  const float o0 = (v0 - mu) * inv * g[t] + bb[t];
  const float o1 = (v1 - mu) * inv * g[t + 256] + bb[t + 256];
  const float o2 = (v2 - mu) * inv * g[t + 512] + bb[t + 512];
  out[base + t] = o0;
  out[base + t + 256] = o1;
  out[base + t + 512] = o2;
  if (out_bf) {
    out_bf[base + t] = f2bf(o0);
    out_bf[base + t + 256] = f2bf(o1);
    out_bf[base + t + 512] = f2bf(o2);
  }
}

// ---------------------------------------------------------------------------
__global__ void stat_kernel(const float* __restrict__ w_buf, float* __restrict__ out) {
  const int r = threadIdx.x;
  if (r < Rdim) {
    float s = 0.f;
    for (int l = 0; l < Ldim; l++)
      for (int b = 0; b < Bdim; b++) s += w_buf[l * Bdim * Rdim + b * Rdim + r];
    out[r] = s * (1.0f / (Ldim * Bdim));
  }
}

extern "C" void kernel_launch(void* const* d_in, const int* in_sizes, int n_in,
                              void* d_out, int out_size, void* d_ws, size_t ws_size,
                              hipStream_t stream) {
  const float* node = (const float*)d_in[0];   // [B,N,H]
  const float* adj  = (const float*)d_in[1];   // [B,R,N,N]
  const float* relW = (const float*)d_in[2];   // [L,R,H,H]
  const float* relb = (const float*)d_in[3];   // [L,R,H]
  const float* gateW = (const float*)d_in[4];  // [L,H,R]
  const float* gateb = (const float*)d_in[5];  // [L,R]
  const float* outW = (const float*)d_in[6];   // [L,H,H]
  const float* outb = (const float*)d_in[7];   // [L,H]
  const float* ln1g = (const float*)d_in[8];
  const float* ln1b = (const float*)d_in[9];
  const float* fW1 = (const float*)d_in[10];   // [L,H,FF]
  const float* fb1 = (const float*)d_in[11];   // [L,FF]
  const float* fW2 = (const float*)d_in[12];   // [L,FF,H]
  const float* fb2 = (const float*)d_in[13];   // [L,H]
  const float* ln2g = (const float*)d_in[14];
  const float* ln2b = (const float*)d_in[15];

  const long BNH = (long)Bdim * Ndim * Hdim;                 // 12,582,912
  const long BRNN = (long)Bdim * Rdim * Ndim * Ndim;         // 41,943,040
  float* xout = (float*)d_out;
  float* stat = xout + BNH;

  // ws layout
  float* ws = (float*)d_ws;
  float* hidden = ws;                          // [B*N,H] f32
  float* tmp    = ws + BNH;                    // [B*N,H] f32; ffh_bf aliases
  unsigned short* agg_all = (unsigned short*)(ws + 2 * BNH);  // [R][B,N,H] bf16
  unsigned short* xT_bf = agg_all + Rdim * BNH;   // [B,H,N] bf16 (hidden_bf alias)
  unsigned short* merged_bf = xT_bf + BNH;        // [B*N,H] bf16
  unsigned short* adjn_bf = merged_bf + BNH;      // [B,R,N,N] bf16
  unsigned short* relWT = adjn_bf + BRNN;         // [L*R,H,H] bf16
  unsigned short* outWT = relWT + (long)Ldim * Rdim * Hdim * Hdim;
  unsigned short* W1T = outWT + (long)Ldim * Hdim * Hdim;
  unsigned short* W2T = W1T + (long)Ldim * Hdim * FFdim;
  float* w_buf = (float*)(W2T + (long)Ldim * FFdim * Hdim);   // [L,B,R]
  float* part = w_buf + Ldim * Bdim * Rdim;                   // [B,8,H]
  unsigned short* hidden_bf = xT_bf;              // alias (xT dead after agg)
  unsigned short* ffh_bf = (unsigned short*)tmp;  // [B*N,FF] bf16 (aliases tmp)
  float* tmp2 = (float*)agg_all;                  // aliases agg_all (dead after msg)

  // ---- one-time prep ----
  {
    const long rows = (long)Bdim * Rdim * Ndim;  // 81920
    norm_adj_kernel<<<(int)(rows / 4), 256, 0, stream>>>(adj, adjn_bf, rows);
  }
  transpose_cvt<<<dim3(Hdim / 32, Hdim / 32, Ldim * Rdim), 256, 0, stream>>>(relW, relWT, Hdim, Hdim);
  transpose_cvt<<<dim3(Hdim / 32, Hdim / 32, Ldim), 256, 0, stream>>>(outW, outWT, Hdim, Hdim);
  transpose_cvt<<<dim3(FFdim / 32, Hdim / 32, Ldim), 256, 0, stream>>>(fW1, W1T, Hdim, FFdim);
  transpose_cvt<<<dim3(Hdim / 32, FFdim / 32, Ldim), 256, 0, stream>>>(fW2, W2T, FFdim, Hdim);

  for (int l = 0; l < Ldim; l++) {
    const float* xin = (l == 0) ? node : xout;

    pool_kernel<<<dim3(8, Bdim), 256, 0, stream>>>(xin, part);
    gate_kernel<<<Bdim, Hdim, 0, stream>>>(
        part, gateW + (long)l * Hdim * Rdim, gateb + (long)l * Rdim,
        w_buf + (long)l * Bdim * Rdim);

    // xT_bf[b][h][n] = x[b][n][h]
    transpose_cvt<<<dim3(Hdim / 32, Ndim / 32, Bdim), 256, 0, stream>>>(xin, xT_bf, Ndim, Hdim);

    // agg_all[r][b] = adjn[b,r] @ x[b]   (all relations, z = r*32+b)
    mfma_gemm<0, true, 1><<<dim3(Hdim / 128, Ndim / 128, Bdim * Rdim), 256, 0, stream>>>(
        adjn_bf, (long)Rdim * Ndim * Ndim, (long)Ndim * Ndim, Ndim,
        xT_bf, (long)Hdim * Ndim, Ndim,
        agg_all, (long)Ndim * Hdim, Hdim,
        Ndim, 0, 0, nullptr, nullptr, nullptr);

    // merged = sum_r w[b,r]*relu(agg_r @ relW[l,r] + relb[l,r])  -> bf16
    mfma_gemm<1, true, Rdim><<<dim3(Hdim / 128, (Bdim * Ndim) / 128, 1), 256, 0, stream>>>(
        agg_all, 0, 0, Hdim,
        relWT + (long)l * Rdim * Hdim * Hdim, 0, Hdim,
        merged_bf, 0, Hdim,
        Hdim, BNH, (long)Hdim * Hdim,
        relb + (long)l * Rdim * Hdim, nullptr,
        w_buf + (long)l * Bdim * Rdim);

    // tmp = merged @ out_W + out_b + xin   (residual fused)
    mfma_gemm<2, false, 1><<<dim3(Hdim / 128, (Bdim * Ndim) / 128, 1), 256, 0, stream>>>(
        merged_bf, 0, 0, Hdim,
        outWT + (long)l * Hdim * Hdim, 0, Hdim,
        tmp, 0, Hdim,
        Hdim, 0, 0,
        outb + (long)l * Hdim, xin, nullptr);

    // hidden = LN(tmp)   (+ bf16 copy for ffn1 A)
    ln_kernel<<<Bdim * Ndim, 256, 0, stream>>>(
        tmp, ln1g + (long)l * Hdim, ln1b + (long)l * Hdim, hidden, hidden_bf);

    // ffh = relu(hidden @ W1 + b1)  -> bf16 (aliases tmp, now dead)
    mfma_gemm<3, true, 1><<<dim3(FFdim / 128, (Bdim * Ndim) / 128, 1), 256, 0, stream>>>(
        hidden_bf, 0, 0, Hdim,
        W1T + (long)l * Hdim * FFdim, 0, Hdim,
        ffh_bf, 0, FFdim,
        Hdim, 0, 0,
        fb1 + (long)l * FFdim, nullptr, nullptr);

    // tmp2 = ffh @ W2 + b2 + hidden  (residual fused; aliases agg_all)
    mfma_gemm<2, false, 1><<<dim3(Hdim / 128, (Bdim * Ndim) / 128, 1), 256, 0, stream>>>(
        ffh_bf, 0, 0, FFdim,
        W2T + (long)l * FFdim * Hdim, 0, FFdim,
        tmp2, 0, Hdim,
        FFdim, 0, 0,
        fb2 + (long)l * Hdim, hidden, nullptr);

    // x = LN(tmp2) -> xout
    ln_kernel<<<Bdim * Ndim, 256, 0, stream>>>(
        tmp2, ln2g + (long)l * Hdim, ln2b + (long)l * Hdim, xout, nullptr);
  }

  stat_kernel<<<1, 64, 0, stream>>>(w_buf, stat);
}